// Round 2
// baseline (3981.384 us; speedup 1.0000x reference)
//
#include <hip/hip_runtime.h>
#include <hip/hip_bf16.h>
#include <hip/hip_fp16.h>

// EncoderRNN: emb gather -> biLSTM(L0) -> biLSTM(L1) -> last-step output.
// Decomposition:
//   1) embed gather -> X0 bf16 [T*B, 256]
//   2) GEMM P0: G = X0 @ W0^T + b  (fwd|bwd packed, N=2048), G fp16 [T*B,2048]
//   3) persistent scan S0 (2 dirs x 16 batch-slices, w_hh streamed from L2 as
//      pre-packed MFMA B-fragments) -> Y0 bf16 [T*B, 512]
//   4) GEMM P1: G = Y0 @ W1^T + b
//   5) scan S1 (fwd only) -> out[:, :256] ; bwd-L1 needs only step 0 (h0=c0=0)
//   6) bwd1 elementwise -> out[:, 256:512]

typedef short s8v __attribute__((ext_vector_type(8)));
typedef float f4v __attribute__((ext_vector_type(4)));
typedef unsigned short u16v8 __attribute__((ext_vector_type(8)));

__device__ inline unsigned short f2bf(float x) {
  union { float f; unsigned u; } v; v.f = x;
  unsigned r = v.u + 0x7fffu + ((v.u >> 16) & 1u);
  return (unsigned short)(r >> 16);
}

__device__ inline void gload_lds16(const void* g, void* l) {
  __builtin_amdgcn_global_load_lds((const __attribute__((address_space(1))) unsigned int*)g,
                                   (__attribute__((address_space(3))) unsigned int*)l,
                                   16, 0, 0);
}

__device__ inline float sigm(float x) { return 1.f / (1.f + __expf(-x)); }
__device__ inline float tanh_f(float x) {
  float e = __expf(2.f * x);
  return 1.f - 2.f / (e + 1.f);
}

// ---------------- embedding gather + bf16 cast -------------------------------
// x0[m, col], m = t*256 + b (seq-first), row = emb[idc[b,t]]
__global__ __launch_bounds__(256) void embed_kernel(
    const int* __restrict__ idc, const float* __restrict__ emb,
    unsigned short* __restrict__ x0)
{
  int e = (blockIdx.x * 256 + threadIdx.x) * 8;   // into [32768*256]
  int m = e >> 8;
  int col = e & 255;
  int t = m >> 8, b = m & 255;
  int idx = idc[b * 128 + t];
  const float* src = emb + (size_t)idx * 256 + col;
  float4 lo = *(const float4*)src;
  float4 hi = *(const float4*)(src + 4);
  u16v8 o;
  o[0]=f2bf(lo.x); o[1]=f2bf(lo.y); o[2]=f2bf(lo.z); o[3]=f2bf(lo.w);
  o[4]=f2bf(hi.x); o[5]=f2bf(hi.y); o[6]=f2bf(hi.z); o[7]=f2bf(hi.w);
  *(u16v8*)(x0 + e) = o;
}

// ---------------- weight packing --------------------------------------------
__global__ __launch_bounds__(256) void pack2_bf16(unsigned short* __restrict__ dst,
    const float* __restrict__ s0, const float* __restrict__ s1, int n_each)
{
  int i = (blockIdx.x * 256 + threadIdx.x) * 4;
  const float* s = (i < n_each) ? (s0 + i) : (s1 + (i - n_each));
  float4 v = *(const float4*)s;
  dst[i] = f2bf(v.x); dst[i+1] = f2bf(v.y); dst[i+2] = f2bf(v.z); dst[i+3] = f2bf(v.w);
}

__global__ __launch_bounds__(256) void pack2_f32(float* __restrict__ dst,
    const float* __restrict__ s0, const float* __restrict__ s1, int n_each)
{
  int i = blockIdx.x * 256 + threadIdx.x;
  dst[i] = (i < n_each) ? s0[i] : s1[i - n_each];
}

// w_hh [1024,256] fp32 -> bf16 MFMA-B-fragment stream:
// dst[((nt*8+ks)*64 + l)*8 + j] = w[(nt*16 + (l&15))*256 + ks*32 + (l>>4)*8 + j]
__global__ __launch_bounds__(256) void pack_whh(short* __restrict__ dst,
                                                const float* __restrict__ w)
{
  int tid = blockIdx.x * 256 + threadIdx.x;   // 0..32767
  int nt = tid >> 9, ks = (tid >> 6) & 7, l = tid & 63;
  const float* src = w + (size_t)(nt*16 + (l & 15))*256 + ks*32 + (l >> 4)*8;
  float4 a = *(const float4*)src;
  float4 b = *(const float4*)(src + 4);
  s8v o;
  o[0]=(short)f2bf(a.x); o[1]=(short)f2bf(a.y); o[2]=(short)f2bf(a.z); o[3]=(short)f2bf(a.w);
  o[4]=(short)f2bf(b.x); o[5]=(short)f2bf(b.y); o[6]=(short)f2bf(b.z); o[7]=(short)f2bf(b.w);
  *(s8v*)(dst + (size_t)tid*8) = o;
}

// ---------------- input-projection GEMM: G = A @ W^T + bias (fp16 out) ------
// A [32768,K] bf16, W [2048,K] bf16, tile 128x128xBK64, 4 waves, dbl-buf LDS.
__global__ __launch_bounds__(256, 2) void gemm_bt(
    const unsigned short* __restrict__ A, const unsigned short* __restrict__ W,
    const float* __restrict__ bias, _Float16* __restrict__ Gout, int K)
{
  __shared__ char lds[65536];     // 2 x (A 16K + B 16K)
  const int tid = threadIdx.x, l = tid & 63, w = tid >> 6;
  const int m0 = blockIdx.x * 128, n0 = blockIdx.y * 128;
  const int wr = w >> 1, wc = w & 1;
  const int NK = K >> 6;
  const int c15 = l & 15, ld4 = l >> 4;

  f4v acc[4][4];
  #pragma unroll
  for (int i = 0; i < 4; ++i)
    #pragma unroll
    for (int j = 0; j < 4; ++j) acc[i][j] = (f4v){0.f,0.f,0.f,0.f};

  auto stage = [&](int kt, int buf) {
    char* base = lds + buf*32768;
    const unsigned short* As = A + (size_t)m0*K + kt*64;
    const unsigned short* Ws = W + (size_t)n0*K + kt*64;
    int rr8 = l >> 3;
    int sl = (l & 7) ^ rr8;          // pre-swizzled source slot (m173 pattern)
    #pragma unroll
    for (int j = 0; j < 4; ++j) {
      int rb = (w*4 + j)*8;
      gload_lds16(As + (size_t)(rb + rr8)*K + sl*8, base + (w*4+j)*1024);
      gload_lds16(Ws + (size_t)(rb + rr8)*K + sl*8, base + 16384 + (w*4+j)*1024);
    }
  };

  stage(0, 0);
  __syncthreads();
  for (int kt = 0; kt < NK; ++kt) {
    const int cur = kt & 1;
    if (kt + 1 < NK) stage(kt+1, cur^1);
    const char* ab = lds + cur*32768;
    const char* bb = ab + 16384;
    #pragma unroll
    for (int ks = 0; ks < 2; ++ks) {
      s8v af[4], bf[4];
      #pragma unroll
      for (int mt = 0; mt < 4; ++mt) {
        int row = wr*64 + mt*16 + c15;
        int cb = ks*64 + ld4*16;
        af[mt] = *(const s8v*)(ab + row*128 + (cb ^ ((row & 7) << 4)));
      }
      #pragma unroll
      for (int nt = 0; nt < 4; ++nt) {
        int row = wc*64 + nt*16 + c15;
        int cb = ks*64 + ld4*16;
        bf[nt] = *(const s8v*)(bb + row*128 + (cb ^ ((row & 7) << 4)));
      }
      #pragma unroll
      for (int mt = 0; mt < 4; ++mt)
        #pragma unroll
        for (int nt = 0; nt < 4; ++nt)
          acc[mt][nt] = __builtin_amdgcn_mfma_f32_16x16x32_bf16(af[mt], bf[nt], acc[mt][nt], 0, 0, 0);
    }
    __syncthreads();
  }
  #pragma unroll
  for (int nt = 0; nt < 4; ++nt) {
    int n = n0 + wc*64 + nt*16 + c15;
    float bv = bias[n];
    #pragma unroll
    for (int mt = 0; mt < 4; ++mt) {
      int mb = m0 + wr*64 + mt*16 + ld4*4;
      #pragma unroll
      for (int j = 0; j < 4; ++j)
        Gout[(size_t)(mb + j)*2048 + n] = (_Float16)(acc[mt][nt][j] + bv);
    }
  }
}

// ---------------- persistent LSTM scan --------------------------------------
// One WG = one (direction, 16-batch slice); 4 waves; wave w owns hidden dims
// [64w,64w+64). Per step: gates = h @ w_hh^T (MFMA, B streamed from L2) +
// G[t] (staged to LDS via global_load_lds); c in regs fp32; h bf16 in
// XOR-swizzled LDS (double buffered). y0 written bf16 for the next layer.
__global__ __launch_bounds__(256, 1) void scan_kernel(
    const _Float16* __restrict__ G,     // [T,256,2048] (+dir*1024 col offset)
    const short* __restrict__ whhF, const short* __restrict__ whhB,
    unsigned short* __restrict__ y0,    // [T,256,512] bf16 or null
    float* __restrict__ fout,           // [256,512] final h (cols 0:256) or null
    int T)
{
  __shared__ char lds[16*1024 + 64*1024];
  char* hbuf = lds;                 // 2 x [16][256] bf16 (swizzled), 8 KB each
  char* gbuf = lds + 16*1024;       // 2 x [16][1024] fp16, 32 KB each

  const int tid = threadIdx.x;
  const int l = tid & 63;
  const int w = tid >> 6;
  const int dir = blockIdx.y;
  const int b0 = blockIdx.x * 16;
  const short* __restrict__ whh = dir ? whhB : whhF;
  const int ld4 = l >> 4;
  const int c15 = l & 15;

  { // zero both h buffers
    int* p = (int*)lds;
    #pragma unroll
    for (int i = 0; i < 16; ++i) p[tid + 256*i] = 0;
  }

  float cst[16];
  #pragma unroll
  for (int i = 0; i < 16; ++i) cst[i] = 0.f;

  { // prologue: stage G[step 0] -> gbuf[0]
    int teff0 = dir ? (T - 1) : 0;
    const char* base = (const char*)(G + ((size_t)teff0*256 + b0)*2048 + dir*1024);
    #pragma unroll
    for (int j = 0; j < 8; ++j) {
      int r = (w*8 + j) >> 1;
      gload_lds16(base + (size_t)r*4096 + ((j&1)*64 + l)*16, gbuf + (w*8 + j)*1024);
    }
  }
  __syncthreads();

  const s8v* __restrict__ wv = (const s8v*)whh;

  for (int t = 0; t < T; ++t) {
    const int cur = t & 1;
    const char* hb = hbuf + cur*8192;

    // A fragments: row = batch = l&15, k = ks*32 + (l>>4)*8 + j
    s8v a[8];
    #pragma unroll
    for (int ks = 0; ks < 8; ++ks) {
      int row = c15;
      int cb = ks*64 + ld4*16;
      a[ks] = *(const s8v*)(hb + row*512 + (cb ^ ((row & 7) << 4)));
    }

    f4v acc[16];                     // i = gate*4 + ht
    #pragma unroll
    for (int i = 0; i < 16; ++i) acc[i] = (f4v){0.f,0.f,0.f,0.f};

    s8v bA[8], bB[8];
#define LDB(i, dst) { const s8v* bp = wv + (size_t)(((i)>>2)*16 + 4*w + ((i)&3))*512 + l; \
      _Pragma("unroll") for (int ks = 0; ks < 8; ++ks) dst[ks] = bp[ks*64]; }
#define MM(i, src) { _Pragma("unroll") for (int ks = 0; ks < 8; ++ks) \
      acc[i] = __builtin_amdgcn_mfma_f32_16x16x32_bf16(a[ks], src[ks], acc[i], 0, 0, 0); }

    LDB(0, bA);
    #pragma unroll
    for (int i = 0; i < 16; i += 2) {
      if (i + 1 < 16) LDB(i+1, bB);
      MM(i, bA);
      if (i + 2 < 16) LDB(i+2, bA);
      MM(i+1, bB);
    }
#undef LDB
#undef MM

    // stage next step's gates (issued after B-stream so vmcnt FIFO doesn't
    // stall the MFMAs on these; drained by the barrier below)
    if (t + 1 < T) {
      int teff1 = dir ? (T - 2 - t) : (t + 1);
      const char* base = (const char*)(G + ((size_t)teff1*256 + b0)*2048 + dir*1024);
      char* gb1 = gbuf + (cur ^ 1)*32768;
      #pragma unroll
      for (int j = 0; j < 8; ++j) {
        int r = (w*8 + j) >> 1;
        gload_lds16(base + (size_t)r*4096 + ((j&1)*64 + l)*16, gb1 + (w*8 + j)*1024);
      }
    }

    // epilogue: gates -> c,h ; write h (swizzled LDS + y0/fout)
    const _Float16* gb = (const _Float16*)(gbuf + cur*32768);
    char* hn = hbuf + (cur ^ 1)*8192;
    const int teff = dir ? (T - 1 - t) : t;
    const bool last = (t == T - 1);
    #pragma unroll
    for (int ht = 0; ht < 4; ++ht) {
      const int hd = (4*w + ht)*16 + c15;
      #pragma unroll
      for (int r = 0; r < 4; ++r) {
        const int row = ld4*4 + r;
        const _Float16* gr = gb + row*1024 + hd;
        float pi = acc[ht][r]      + (float)gr[0];
        float pf = acc[4 + ht][r]  + (float)gr[256];
        float pg = acc[8 + ht][r]  + (float)gr[512];
        float po = acc[12 + ht][r] + (float)gr[768];
        float cn = sigm(pf) * cst[ht*4 + r] + sigm(pi) * tanh_f(pg);
        cst[ht*4 + r] = cn;
        float hv = sigm(po) * tanh_f(cn);
        unsigned short hb16 = f2bf(hv);
        int cb = hd * 2;
        *(unsigned short*)(hn + row*512 + (cb ^ ((row & 7) << 4))) = hb16;
        if (y0) y0[((size_t)teff*256 + b0 + row)*512 + dir*256 + hd] = hb16;
        if (fout && last) fout[(b0 + row)*512 + hd] = hv;
      }
    }
    __syncthreads();
  }
}

// ---------------- layer-1 backward: only its first step reaches the output --
// yb1[127] = one LSTM step on y0[127] with h0=c0=0 (so h@w_hh term vanishes).
__global__ __launch_bounds__(256) void bwd1_kernel(const _Float16* __restrict__ G,
                                                   float* __restrict__ out)
{
  int tid = blockIdx.x * 256 + threadIdx.x;   // 65536 = 256 b x 256 hd
  int b = tid >> 8, hd = tid & 255;
  const _Float16* g = G + ((size_t)(127*256 + b))*2048 + 1024;
  float pi = (float)g[hd];
  float pg = (float)g[512 + hd];
  float po = (float)g[768 + hd];
  float cn = sigm(pi) * tanh_f(pg);
  out[b*512 + 256 + hd] = sigm(po) * tanh_f(cn);
}

// ---------------- launch -----------------------------------------------------
extern "C" void kernel_launch(void* const* d_in, const int* in_sizes, int n_in,
                              void* d_out, int out_size, void* d_ws, size_t ws_size,
                              hipStream_t stream)
{
  (void)in_sizes; (void)n_in; (void)out_size; (void)ws_size;
  const int*   idc   = (const int*)d_in[0];
  const float* emb   = (const float*)d_in[1];
  const float* wih0f = (const float*)d_in[2];
  const float* whh0f = (const float*)d_in[3];
  const float* b0f   = (const float*)d_in[4];
  const float* wih0b = (const float*)d_in[5];
  const float* whh0b = (const float*)d_in[6];
  const float* b0b   = (const float*)d_in[7];
  const float* wih1f = (const float*)d_in[8];
  const float* whh1f = (const float*)d_in[9];
  const float* b1f   = (const float*)d_in[10];
  const float* wih1b = (const float*)d_in[11];
  const float* b1b   = (const float*)d_in[13];

  char* ws = (char*)d_ws;                                   // ~189.3 MB used
  unsigned short* X0   = (unsigned short*)(ws);             // 16,777,216 B
  unsigned short* Y0   = (unsigned short*)(ws + 16777216);  // 33,554,432 B
  _Float16*       Gb   = (_Float16*)(ws + 50331648);        // 134,217,728 B
  unsigned short* W0P  = (unsigned short*)(ws + 184549376); // 1,048,576 B
  unsigned short* W1P  = (unsigned short*)(ws + 185597952); // 2,097,152 B
  short*          WH0F = (short*)(ws + 187695104);          // 524,288 B
  short*          WH0B = (short*)(ws + 188219392);          // 524,288 B
  short*          WH1F = (short*)(ws + 188743680);          // 524,288 B
  float*          B0P  = (float*)(ws + 189267968);          // 8,192 B
  float*          B1P  = (float*)(ws + 189276160);          // 8,192 B
  float* out = (float*)d_out;

  embed_kernel<<<dim3(4096), dim3(256), 0, stream>>>(idc, emb, X0);
  pack2_bf16<<<dim3(512),  dim3(256), 0, stream>>>(W0P, wih0f, wih0b, 262144);
  pack2_bf16<<<dim3(1024), dim3(256), 0, stream>>>(W1P, wih1f, wih1b, 524288);
  pack2_f32 <<<dim3(8),    dim3(256), 0, stream>>>(B0P, b0f, b0b, 1024);
  pack2_f32 <<<dim3(8),    dim3(256), 0, stream>>>(B1P, b1f, b1b, 1024);
  pack_whh  <<<dim3(128),  dim3(256), 0, stream>>>(WH0F, whh0f);
  pack_whh  <<<dim3(128),  dim3(256), 0, stream>>>(WH0B, whh0b);
  pack_whh  <<<dim3(128),  dim3(256), 0, stream>>>(WH1F, whh1f);

  gemm_bt<<<dim3(256, 16), dim3(256), 0, stream>>>(X0, W0P, B0P, Gb, 256);
  scan_kernel<<<dim3(16, 2), dim3(256), 0, stream>>>(Gb, WH0F, WH0B, Y0, (float*)nullptr, 128);
  gemm_bt<<<dim3(256, 16), dim3(256), 0, stream>>>(Y0, W1P, B1P, Gb, 512);
  scan_kernel<<<dim3(16, 1), dim3(256), 0, stream>>>(Gb, WH1F, WH1F, (unsigned short*)nullptr, out, 128);
  bwd1_kernel<<<dim3(256), dim3(256), 0, stream>>>(Gb, out);
}

// Round 3
// 2598.529 us; speedup vs baseline: 1.5322x; 1.5322x over previous
//
#include <hip/hip_runtime.h>
#include <hip/hip_bf16.h>
#include <hip/hip_fp16.h>

// EncoderRNN: emb gather -> biLSTM(L0) -> biLSTM(L1) -> last-step output.
//   1) embed gather -> X0 bf16 [T*B, 256]
//   2) GEMM P0: G = X0 @ W0^T + b  (fwd|bwd packed, N=2048), G fp16 [T*B,2048]
//   3) scan S0 (2 dirs x 16 batch-slices, 8 waves/WG, w_hh streamed from L2)
//   4) GEMM P1: fwd cols only (N=1024) + tiny t=127 bwd GEMM
//   5) scan S1 (fwd only) -> out[:, :256]
//   6) bwd1 elementwise (t=127, h0=c0=0) -> out[:, 256:512]

typedef short s8v __attribute__((ext_vector_type(8)));
typedef float f4v __attribute__((ext_vector_type(4)));
typedef unsigned short u16v8 __attribute__((ext_vector_type(8)));

__device__ inline unsigned short f2bf(float x) {
  union { float f; unsigned u; } v; v.f = x;
  unsigned r = v.u + 0x7fffu + ((v.u >> 16) & 1u);
  return (unsigned short)(r >> 16);
}

__device__ inline void gload_lds16(const void* g, void* l) {
  __builtin_amdgcn_global_load_lds((const __attribute__((address_space(1))) unsigned int*)g,
                                   (__attribute__((address_space(3))) unsigned int*)l,
                                   16, 0, 0);
}

__device__ inline float sigm(float x) { return 1.f / (1.f + __expf(-x)); }
__device__ inline float tanh_f(float x) {
  float e = __expf(2.f * x);
  return 1.f - 2.f / (e + 1.f);
}

// ---------------- embedding gather + bf16 cast -------------------------------
__global__ __launch_bounds__(256) void embed_kernel(
    const int* __restrict__ idc, const float* __restrict__ emb,
    unsigned short* __restrict__ x0)
{
  int e = (blockIdx.x * 256 + threadIdx.x) * 8;   // into [32768*256]
  int m = e >> 8;
  int col = e & 255;
  int t = m >> 8, b = m & 255;
  int idx = idc[b * 128 + t];
  const float* src = emb + (size_t)idx * 256 + col;
  float4 lo = *(const float4*)src;
  float4 hi = *(const float4*)(src + 4);
  u16v8 o;
  o[0]=f2bf(lo.x); o[1]=f2bf(lo.y); o[2]=f2bf(lo.z); o[3]=f2bf(lo.w);
  o[4]=f2bf(hi.x); o[5]=f2bf(hi.y); o[6]=f2bf(hi.z); o[7]=f2bf(hi.w);
  *(u16v8*)(x0 + e) = o;
}

// ---------------- weight packing --------------------------------------------
__global__ __launch_bounds__(256) void pack2_bf16(unsigned short* __restrict__ dst,
    const float* __restrict__ s0, const float* __restrict__ s1, int n_each)
{
  int i = (blockIdx.x * 256 + threadIdx.x) * 4;
  const float* s = (i < n_each) ? (s0 + i) : (s1 + (i - n_each));
  float4 v = *(const float4*)s;
  dst[i] = f2bf(v.x); dst[i+1] = f2bf(v.y); dst[i+2] = f2bf(v.z); dst[i+3] = f2bf(v.w);
}

__global__ __launch_bounds__(256) void pack2_f32(float* __restrict__ dst,
    const float* __restrict__ s0, const float* __restrict__ s1, int n_each)
{
  int i = blockIdx.x * 256 + threadIdx.x;
  dst[i] = (i < n_each) ? s0[i] : s1[i - n_each];
}

// w_hh [1024,256] fp32 -> bf16 MFMA-B-fragment stream:
// dst[((nt*8+ks)*64 + l)*8 + j] = w[(nt*16 + (l&15))*256 + ks*32 + (l>>4)*8 + j]
__global__ __launch_bounds__(256) void pack_whh(short* __restrict__ dst,
                                                const float* __restrict__ w)
{
  int tid = blockIdx.x * 256 + threadIdx.x;   // 0..32767
  int nt = tid >> 9, ks = (tid >> 6) & 7, l = tid & 63;
  const float* src = w + (size_t)(nt*16 + (l & 15))*256 + ks*32 + (l >> 4)*8;
  float4 a = *(const float4*)src;
  float4 b = *(const float4*)(src + 4);
  s8v o;
  o[0]=(short)f2bf(a.x); o[1]=(short)f2bf(a.y); o[2]=(short)f2bf(a.z); o[3]=(short)f2bf(a.w);
  o[4]=(short)f2bf(b.x); o[5]=(short)f2bf(b.y); o[6]=(short)f2bf(b.z); o[7]=(short)f2bf(b.w);
  *(s8v*)(dst + (size_t)tid*8) = o;
}

// ---------------- input-projection GEMM: G = A @ W^T + bias (fp16 out) ------
__global__ __launch_bounds__(256, 2) void gemm_bt(
    const unsigned short* __restrict__ A, const unsigned short* __restrict__ W,
    const float* __restrict__ bias, _Float16* __restrict__ Gout, int K)
{
  __shared__ char lds[65536];     // 2 x (A 16K + B 16K)
  const int tid = threadIdx.x, l = tid & 63, w = tid >> 6;
  const int m0 = blockIdx.x * 128, n0 = blockIdx.y * 128;
  const int wr = w >> 1, wc = w & 1;
  const int NK = K >> 6;
  const int c15 = l & 15, ld4 = l >> 4;

  f4v acc[4][4];
  #pragma unroll
  for (int i = 0; i < 4; ++i)
    #pragma unroll
    for (int j = 0; j < 4; ++j) acc[i][j] = (f4v){0.f,0.f,0.f,0.f};

  auto stage = [&](int kt, int buf) {
    char* base = lds + buf*32768;
    const unsigned short* As = A + (size_t)m0*K + kt*64;
    const unsigned short* Ws = W + (size_t)n0*K + kt*64;
    int rr8 = l >> 3;
    int sl = (l & 7) ^ rr8;          // pre-swizzled source slot
    #pragma unroll
    for (int j = 0; j < 4; ++j) {
      int rb = (w*4 + j)*8;
      gload_lds16(As + (size_t)(rb + rr8)*K + sl*8, base + (w*4+j)*1024);
      gload_lds16(Ws + (size_t)(rb + rr8)*K + sl*8, base + 16384 + (w*4+j)*1024);
    }
  };

  stage(0, 0);
  __syncthreads();
  for (int kt = 0; kt < NK; ++kt) {
    const int cur = kt & 1;
    if (kt + 1 < NK) stage(kt+1, cur^1);
    const char* ab = lds + cur*32768;
    const char* bb = ab + 16384;
    #pragma unroll
    for (int ks = 0; ks < 2; ++ks) {
      s8v af[4], bf[4];
      #pragma unroll
      for (int mt = 0; mt < 4; ++mt) {
        int row = wr*64 + mt*16 + c15;
        int cb = ks*64 + ld4*16;
        af[mt] = *(const s8v*)(ab + row*128 + (cb ^ ((row & 7) << 4)));
      }
      #pragma unroll
      for (int nt = 0; nt < 4; ++nt) {
        int row = wc*64 + nt*16 + c15;
        int cb = ks*64 + ld4*16;
        bf[nt] = *(const s8v*)(bb + row*128 + (cb ^ ((row & 7) << 4)));
      }
      #pragma unroll
      for (int mt = 0; mt < 4; ++mt)
        #pragma unroll
        for (int nt = 0; nt < 4; ++nt)
          acc[mt][nt] = __builtin_amdgcn_mfma_f32_16x16x32_bf16(af[mt], bf[nt], acc[mt][nt], 0, 0, 0);
    }
    __syncthreads();
  }
  #pragma unroll
  for (int nt = 0; nt < 4; ++nt) {
    int n = n0 + wc*64 + nt*16 + c15;
    float bv = bias[n];
    #pragma unroll
    for (int mt = 0; mt < 4; ++mt) {
      int mb = m0 + wr*64 + mt*16 + ld4*4;
      #pragma unroll
      for (int j = 0; j < 4; ++j)
        Gout[(size_t)(mb + j)*2048 + n] = (_Float16)(acc[mt][nt][j] + bv);
    }
  }
}

// ---------------- persistent LSTM scan --------------------------------------
// One WG = (direction, 16-batch slice); 8 waves (512 thr). Wave w owns hidden
// dims [32w, 32w+32) across all 4 gates (n-tiles nt = g*16 + 2w + p).
// Per step: gates = h @ w_hh^T (MFMA, B streamed from L2, double-buffered in
// regs) + G[t] (LDS, staged early via global_load_lds); c fp32 in regs; h bf16
// in XOR-swizzled LDS (double buffered).
__global__ __launch_bounds__(512, 1) void scan_kernel(
    const _Float16* __restrict__ G,     // [T,256,2048] (+dir*1024 col offset)
    const short* __restrict__ whhF, const short* __restrict__ whhB,
    unsigned short* __restrict__ y0,    // [T,256,512] bf16 or null
    float* __restrict__ fout,           // [256,512] final h (cols 0:256) or null
    int T)
{
  __shared__ char lds[16*1024 + 64*1024];
  char* hbuf = lds;                 // 2 x [16][256] bf16 (swizzled), 8 KB each
  char* gbuf = lds + 16*1024;       // 2 x [16][1024] fp16, 32 KB each

  const int tid = threadIdx.x;      // 0..511
  const int l = tid & 63;
  const int w = tid >> 6;           // 0..7
  const int dir = blockIdx.y;
  const int b0 = blockIdx.x * 16;
  const short* __restrict__ whh = dir ? whhB : whhF;
  const int ld4 = l >> 4;
  const int c15 = l & 15;

  { // zero both h buffers (16 KB)
    int* p = (int*)lds;
    #pragma unroll
    for (int i = 0; i < 8; ++i) p[tid + 512*i] = 0;
  }

  float cst[8];
  #pragma unroll
  for (int i = 0; i < 8; ++i) cst[i] = 0.f;

  { // prologue: stage G[step 0] -> gbuf[0]
    int teff0 = dir ? (T - 1) : 0;
    const char* base = (const char*)(G + ((size_t)teff0*256 + b0)*2048 + dir*1024);
    #pragma unroll
    for (int j = 0; j < 4; ++j) {
      int q = w*4 + j;
      gload_lds16(base + (size_t)(q >> 1)*4096 + ((q & 1)*64 + l)*16, gbuf + q*1024);
    }
  }
  __syncthreads();

  const s8v* __restrict__ wv = (const s8v*)whh;

  for (int t = 0; t < T; ++t) {
    const int cur = t & 1;
    const char* hb = hbuf + cur*8192;

    // A fragments: row = batch = l&15, k = ks*32 + (l>>4)*8 + j
    s8v a[8];
    #pragma unroll
    for (int ks = 0; ks < 8; ++ks) {
      int cb = ks*64 + ld4*16;
      a[ks] = *(const s8v*)(hb + c15*512 + (cb ^ ((c15 & 7) << 4)));
    }

    // stage next step's G early: latency hides under the B-stream below
    if (t + 1 < T) {
      int teff1 = dir ? (T - 2 - t) : (t + 1);
      const char* base = (const char*)(G + ((size_t)teff1*256 + b0)*2048 + dir*1024);
      char* gb1 = gbuf + (cur ^ 1)*32768;
      #pragma unroll
      for (int j = 0; j < 4; ++j) {
        int q = w*4 + j;
        gload_lds16(base + (size_t)(q >> 1)*4096 + ((q & 1)*64 + l)*16, gb1 + q*1024);
      }
    }

    f4v acc[8];                      // i = g*2 + p
    #pragma unroll
    for (int i = 0; i < 8; ++i) acc[i] = (f4v){0.f,0.f,0.f,0.f};

    s8v bA[8], bB[8];
#define LDB(i, dst) { const s8v* bp = wv + (size_t)(((((i)>>1)*16 + 2*w + ((i)&1))*8))*64 + l; \
      _Pragma("unroll") for (int ks = 0; ks < 8; ++ks) dst[ks] = bp[ks*64]; }
#define MM(i, src) { _Pragma("unroll") for (int ks = 0; ks < 8; ++ks) \
      acc[i] = __builtin_amdgcn_mfma_f32_16x16x32_bf16(a[ks], src[ks], acc[i], 0, 0, 0); }

    LDB(0, bA);
    #pragma unroll
    for (int i = 0; i < 8; i += 2) {
      LDB(i+1, bB);
      MM(i, bA);
      if (i + 2 < 8) LDB(i+2, bA);
      MM(i+1, bB);
    }
#undef LDB
#undef MM

    // epilogue: gates -> c,h ; write h (swizzled LDS + y0/fout)
    const _Float16* gb = (const _Float16*)(gbuf + cur*32768);
    char* hn = hbuf + (cur ^ 1)*8192;
    const int teff = dir ? (T - 1 - t) : t;
    const bool last = (t == T - 1);
    #pragma unroll
    for (int p = 0; p < 2; ++p) {
      const int hd = 32*w + 16*p + c15;
      #pragma unroll
      for (int r = 0; r < 4; ++r) {
        const int row = ld4*4 + r;
        const _Float16* gr = gb + row*1024 + hd;
        float pi = acc[0 + p][r] + (float)gr[0];
        float pf = acc[2 + p][r] + (float)gr[256];
        float pg = acc[4 + p][r] + (float)gr[512];
        float po = acc[6 + p][r] + (float)gr[768];
        float cn = sigm(pf) * cst[p*4 + r] + sigm(pi) * tanh_f(pg);
        cst[p*4 + r] = cn;
        float hv = sigm(po) * tanh_f(cn);
        unsigned short hb16 = f2bf(hv);
        int cb = hd * 2;
        *(unsigned short*)(hn + row*512 + (cb ^ ((row & 7) << 4))) = hb16;
        if (y0) y0[((size_t)teff*256 + b0 + row)*512 + dir*256 + hd] = hb16;
        if (fout && last) fout[(b0 + row)*512 + hd] = hv;
      }
    }
    __syncthreads();
  }
}

// ---------------- layer-1 backward: only its first step reaches the output --
__global__ __launch_bounds__(256) void bwd1_kernel(const _Float16* __restrict__ G,
                                                   float* __restrict__ out)
{
  int tid = blockIdx.x * 256 + threadIdx.x;   // 65536 = 256 b x 256 hd
  int b = tid >> 8, hd = tid & 255;
  const _Float16* g = G + ((size_t)(127*256 + b))*2048 + 1024;
  float pi = (float)g[hd];
  float pg = (float)g[512 + hd];
  float po = (float)g[768 + hd];
  float cn = sigm(pi) * tanh_f(pg);
  out[b*512 + 256 + hd] = sigm(po) * tanh_f(cn);
}

// ---------------- launch -----------------------------------------------------
extern "C" void kernel_launch(void* const* d_in, const int* in_sizes, int n_in,
                              void* d_out, int out_size, void* d_ws, size_t ws_size,
                              hipStream_t stream)
{
  (void)in_sizes; (void)n_in; (void)out_size; (void)ws_size;
  const int*   idc   = (const int*)d_in[0];
  const float* emb   = (const float*)d_in[1];
  const float* wih0f = (const float*)d_in[2];
  const float* whh0f = (const float*)d_in[3];
  const float* b0f   = (const float*)d_in[4];
  const float* wih0b = (const float*)d_in[5];
  const float* whh0b = (const float*)d_in[6];
  const float* b0b   = (const float*)d_in[7];
  const float* wih1f = (const float*)d_in[8];
  const float* whh1f = (const float*)d_in[9];
  const float* b1f   = (const float*)d_in[10];
  const float* wih1b = (const float*)d_in[11];
  const float* b1b   = (const float*)d_in[13];

  char* ws = (char*)d_ws;                                   // ~189.3 MB used
  unsigned short* X0   = (unsigned short*)(ws);             // 16,777,216 B
  unsigned short* Y0   = (unsigned short*)(ws + 16777216);  // 33,554,432 B
  _Float16*       Gb   = (_Float16*)(ws + 50331648);        // 134,217,728 B
  unsigned short* W0P  = (unsigned short*)(ws + 184549376); // 1,048,576 B
  unsigned short* W1P  = (unsigned short*)(ws + 185597952); // 2,097,152 B
  short*          WH0F = (short*)(ws + 187695104);          // 524,288 B
  short*          WH0B = (short*)(ws + 188219392);          // 524,288 B
  short*          WH1F = (short*)(ws + 188743680);          // 524,288 B
  float*          B0P  = (float*)(ws + 189267968);          // 8,192 B
  float*          B1P  = (float*)(ws + 189276160);          // 8,192 B
  float* out = (float*)d_out;

  embed_kernel<<<dim3(4096), dim3(256), 0, stream>>>(idc, emb, X0);
  pack2_bf16<<<dim3(512),  dim3(256), 0, stream>>>(W0P, wih0f, wih0b, 262144);
  pack2_bf16<<<dim3(1024), dim3(256), 0, stream>>>(W1P, wih1f, wih1b, 524288);
  pack2_f32 <<<dim3(8),    dim3(256), 0, stream>>>(B0P, b0f, b0b, 1024);
  pack2_f32 <<<dim3(8),    dim3(256), 0, stream>>>(B1P, b1f, b1b, 1024);
  pack_whh  <<<dim3(128),  dim3(256), 0, stream>>>(WH0F, whh0f);
  pack_whh  <<<dim3(128),  dim3(256), 0, stream>>>(WH0B, whh0b);
  pack_whh  <<<dim3(128),  dim3(256), 0, stream>>>(WH1F, whh1f);

  // L0: full gate GEMM (both dirs) + bi-directional scan
  gemm_bt<<<dim3(256, 16), dim3(256), 0, stream>>>(X0, W0P, B0P, Gb, 256);
  scan_kernel<<<dim3(16, 2), dim3(512), 0, stream>>>(Gb, WH0F, WH0B, Y0, (float*)nullptr, 128);

  // L1: fwd gates for all t (N=1024) ...
  gemm_bt<<<dim3(256, 8), dim3(256), 0, stream>>>(Y0, W1P, B1P, Gb, 512);
  // ... + bwd gates only for t=127 (rows 127*256..), cols 1024:2048
  gemm_bt<<<dim3(2, 8), dim3(256), 0, stream>>>(
      Y0 + (size_t)127*256*512, W1P + (size_t)1024*512, B1P + 1024,
      Gb + (size_t)127*256*2048 + 1024, 512);

  scan_kernel<<<dim3(16, 1), dim3(512), 0, stream>>>(Gb, WH1F, WH1F, (unsigned short*)nullptr, out, 128);
  bwd1_kernel<<<dim3(256), dim3(256), 0, stream>>>(Gb, out);
}

// Round 6
// 1596.207 us; speedup vs baseline: 2.4943x; 1.6279x over previous
//
#include <hip/hip_runtime.h>
#include <hip/hip_bf16.h>
#include <hip/hip_fp16.h>

// EncoderRNN: emb gather -> biLSTM(L0) -> biLSTM(L1) -> last-step output.
//   1) embed gather -> X0 bf16 [T*B, 256]
//   2) GEMM P0: G = X0 @ W0^T + b (fwd|bwd packed, N=2048), G fp16 [T*B,2048]
//   3) scan S0: per (dir, 32-batch dslice) recurrence split across 4 WGs
//      (one hidden-quarter each, weights LDS-resident); h exchanged through
//      Y0 (touch-once addresses) with device-scope flag sync
//   4) GEMM P1: fwd cols (N=1024) + tiny t=127 bwd GEMM
//   5) scan S1 (fwd only), h exchanged through dead X0 region -> out[:, :256]
//   6) bwd1 elementwise (t=127, h0=c0=0) -> out[:, 256:512]

typedef short s8v __attribute__((ext_vector_type(8)));
typedef float f4v __attribute__((ext_vector_type(4)));
typedef unsigned short u16v8 __attribute__((ext_vector_type(8)));

__device__ inline unsigned short f2bf(float x) {
  union { float f; unsigned u; } v; v.f = x;
  unsigned r = v.u + 0x7fffu + ((v.u >> 16) & 1u);
  return (unsigned short)(r >> 16);
}

__device__ inline void gload_lds16(const void* g, void* l) {
  __builtin_amdgcn_global_load_lds((const __attribute__((address_space(1))) unsigned int*)g,
                                   (__attribute__((address_space(3))) unsigned int*)l,
                                   16, 0, 0);
}

__device__ inline float sigm(float x) { return 1.f / (1.f + __expf(-x)); }
__device__ inline float tanh_f(float x) {
  float e = __expf(2.f * x);
  return 1.f - 2.f / (e + 1.f);
}

// ---------------- embedding gather + bf16 cast -------------------------------
__global__ __launch_bounds__(256) void embed_kernel(
    const int* __restrict__ idc, const float* __restrict__ emb,
    unsigned short* __restrict__ x0)
{
  int e = (blockIdx.x * 256 + threadIdx.x) * 8;   // into [32768*256]
  int m = e >> 8;
  int col = e & 255;
  int t = m >> 8, b = m & 255;
  int idx = idc[b * 128 + t];
  const float* src = emb + (size_t)idx * 256 + col;
  float4 lo = *(const float4*)src;
  float4 hi = *(const float4*)(src + 4);
  u16v8 o;
  o[0]=f2bf(lo.x); o[1]=f2bf(lo.y); o[2]=f2bf(lo.z); o[3]=f2bf(lo.w);
  o[4]=f2bf(hi.x); o[5]=f2bf(hi.y); o[6]=f2bf(hi.z); o[7]=f2bf(hi.w);
  *(u16v8*)(x0 + e) = o;
}

// ---------------- weight packing --------------------------------------------
__global__ __launch_bounds__(256) void pack2_bf16(unsigned short* __restrict__ dst,
    const float* __restrict__ s0, const float* __restrict__ s1, int n_each)
{
  int i = (blockIdx.x * 256 + threadIdx.x) * 4;
  const float* s = (i < n_each) ? (s0 + i) : (s1 + (i - n_each));
  float4 v = *(const float4*)s;
  dst[i] = f2bf(v.x); dst[i+1] = f2bf(v.y); dst[i+2] = f2bf(v.z); dst[i+3] = f2bf(v.w);
}

__global__ __launch_bounds__(256) void pack2_f32(float* __restrict__ dst,
    const float* __restrict__ s0, const float* __restrict__ s1, int n_each)
{
  int i = blockIdx.x * 256 + threadIdx.x;
  dst[i] = (i < n_each) ? s0[i] : s1[i - n_each];
}

// w_hh [1024,256] fp32 -> bf16 MFMA-B-fragment stream:
// dst[((nt*8+ks)*64 + l)*8 + j] = w[(nt*16 + (l&15))*256 + ks*32 + (l>>4)*8 + j]
__global__ __launch_bounds__(256) void pack_whh(short* __restrict__ dst,
                                                const float* __restrict__ w)
{
  int tid = blockIdx.x * 256 + threadIdx.x;   // 0..32767
  int nt = tid >> 9, ks = (tid >> 6) & 7, l = tid & 63;
  const float* src = w + (size_t)(nt*16 + (l & 15))*256 + ks*32 + (l >> 4)*8;
  float4 a = *(const float4*)src;
  float4 b = *(const float4*)(src + 4);
  s8v o;
  o[0]=(short)f2bf(a.x); o[1]=(short)f2bf(a.y); o[2]=(short)f2bf(a.z); o[3]=(short)f2bf(a.w);
  o[4]=(short)f2bf(b.x); o[5]=(short)f2bf(b.y); o[6]=(short)f2bf(b.z); o[7]=(short)f2bf(b.w);
  *(s8v*)(dst + (size_t)tid*8) = o;
}

// ---------------- input-projection GEMM: G = A @ W^T + bias (fp16 out) ------
__global__ __launch_bounds__(256, 2) void gemm_bt(
    const unsigned short* __restrict__ A, const unsigned short* __restrict__ W,
    const float* __restrict__ bias, _Float16* __restrict__ Gout, int K)
{
  __shared__ char lds[65536];     // 2 x (A 16K + B 16K)
  const int tid = threadIdx.x, l = tid & 63, w = tid >> 6;
  const int m0 = blockIdx.x * 128, n0 = blockIdx.y * 128;
  const int wr = w >> 1, wc = w & 1;
  const int NK = K >> 6;
  const int c15 = l & 15, ld4 = l >> 4;

  f4v acc[4][4];
  #pragma unroll
  for (int i = 0; i < 4; ++i)
    #pragma unroll
    for (int j = 0; j < 4; ++j) acc[i][j] = (f4v){0.f,0.f,0.f,0.f};

  auto stage = [&](int kt, int buf) {
    char* base = lds + buf*32768;
    const unsigned short* As = A + (size_t)m0*K + kt*64;
    const unsigned short* Ws = W + (size_t)n0*K + kt*64;
    int rr8 = l >> 3;
    int sl = (l & 7) ^ rr8;          // pre-swizzled source slot
    #pragma unroll
    for (int j = 0; j < 4; ++j) {
      int rb = (w*4 + j)*8;
      gload_lds16(As + (size_t)(rb + rr8)*K + sl*8, base + (w*4+j)*1024);
      gload_lds16(Ws + (size_t)(rb + rr8)*K + sl*8, base + 16384 + (w*4+j)*1024);
    }
  };

  stage(0, 0);
  __syncthreads();
  for (int kt = 0; kt < NK; ++kt) {
    const int cur = kt & 1;
    if (kt + 1 < NK) stage(kt+1, cur^1);
    const char* ab = lds + cur*32768;
    const char* bb = ab + 16384;
    #pragma unroll
    for (int ks = 0; ks < 2; ++ks) {
      s8v af[4], bf[4];
      #pragma unroll
      for (int mt = 0; mt < 4; ++mt) {
        int row = wr*64 + mt*16 + c15;
        int cb = ks*64 + ld4*16;
        af[mt] = *(const s8v*)(ab + row*128 + (cb ^ ((row & 7) << 4)));
      }
      #pragma unroll
      for (int nt = 0; nt < 4; ++nt) {
        int row = wc*64 + nt*16 + c15;
        int cb = ks*64 + ld4*16;
        bf[nt] = *(const s8v*)(bb + row*128 + (cb ^ ((row & 7) << 4)));
      }
      #pragma unroll
      for (int mt = 0; mt < 4; ++mt)
        #pragma unroll
        for (int nt = 0; nt < 4; ++nt)
          acc[mt][nt] = __builtin_amdgcn_mfma_f32_16x16x32_bf16(af[mt], bf[nt], acc[mt][nt], 0, 0, 0);
    }
    __syncthreads();
  }
  #pragma unroll
  for (int nt = 0; nt < 4; ++nt) {
    int n = n0 + wc*64 + nt*16 + c15;
    float bv = bias[n];
    #pragma unroll
    for (int mt = 0; mt < 4; ++mt) {
      int mb = m0 + wr*64 + mt*16 + ld4*4;
      #pragma unroll
      for (int j = 0; j < 4; ++j)
        Gout[(size_t)(mb + j)*2048 + n] = (_Float16)(acc[mt][nt][j] + bv);
    }
  }
}

// ---------------- split-recurrence LSTM scan --------------------------------
// Group = (dir, dslice of 32 batch rows); 4 WGs per group, WG = hidden-quarter
// q (64 hd). WG: 8 waves (512 thr); wave w -> slice s=w>>2 (16 rows), subtile
// u=w&3 (16 hd), all 4 gates -> epilogue wave-local. Weights (128 KB) live in
// LDS. h exchange through `hexch` (touch-once [teff][256][hstride]+hcol
// addresses) with device-scope flag sync: writer release-adds cnt[grp][t],
// readers acquire-poll ==4.
__global__ __launch_bounds__(512, 1) void scan_kernel(
    const _Float16* __restrict__ G,     // [T,256,2048] (+dir*1024 col offset)
    const short* __restrict__ whhF, const short* __restrict__ whhB,
    unsigned short* __restrict__ hexch, int hstride,
    float* __restrict__ fout,           // out cols 0:256 (scan1) or null
    int* __restrict__ flags, int T)
{
  __shared__ char lds[147456];      // 128 KB weights + 16 KB G
  char* wlds = lds;
  char* gbuf = lds + 131072;        // [s][g][row 16][64 fp16] = 2*4*2048 B

  const int tid = threadIdx.x;
  const int l = tid & 63;
  const int w = tid >> 6;           // 0..7
  const int ds = blockIdx.x;        // dslice 0..7
  const int dir = blockIdx.y;
  const int q = blockIdx.z;         // hidden quarter 0..3
  const int b0 = ds * 32;
  const int hcol = dir * 256;
  const short* __restrict__ whh = dir ? whhB : whhF;
  int* cnt = flags + (dir*8 + ds) * T;
  const int ld4 = l >> 4;
  const int c15 = l & 15;
  const int s = w >> 2;             // slice within WG
  const int u = w & 3;              // 16-hd subtile within quarter

  // weights -> LDS: idx2 = (g*4+u)*8+ks ; nt = g*16 + q*4 + u
  #pragma unroll
  for (int j = 0; j < 16; ++j) {
    int idx2 = w*16 + j;
    int g = idx2 >> 5, rem = idx2 & 31, uu = rem >> 3, ks = rem & 7;
    int nt = g*16 + q*4 + uu;
    gload_lds16(whh + ((size_t)(nt*8 + ks)*64 + l)*8, wlds + idx2*1024);
  }

  float cst[4];
  #pragma unroll
  for (int i = 0; i < 4; ++i) cst[i] = 0.f;

  for (int t = 0; t < T; ++t) {
    const int teff = dir ? (T - 1 - t) : t;

    // stage this step's G quarter (independent of the flag -> overlaps poll)
    #pragma unroll
    for (int j = 0; j < 2; ++j) {
      const char* gsrc = (const char*)(G +
          ((size_t)(teff*256 + b0 + s*16 + j*8 + (l >> 3)))*2048 +
          dir*1024 + (size_t)(u*256 + q*64)) + (l & 7)*16;
      gload_lds16(gsrc, gbuf + s*8192 + u*2048 + j*1024);
    }

    if (t > 0 && tid == 0) {
      while (__hip_atomic_load(cnt + (t-1), __ATOMIC_ACQUIRE,
                               __HIP_MEMORY_SCOPE_AGENT) < 4) {}
    }
    __syncthreads();   // poll visible to WG; G stage + weight loads drained

    f4v acc[4];
    #pragma unroll
    for (int i = 0; i < 4; ++i) acc[i] = (f4v){0.f,0.f,0.f,0.f};

    if (t > 0) {
      const int tprev = dir ? (T - t) : (t - 1);
      s8v a[8];
      const unsigned short* hp = hexch +
          ((size_t)tprev*256 + b0 + s*16 + c15)*hstride + hcol + ld4*8;
      #pragma unroll
      for (int ks = 0; ks < 8; ++ks) a[ks] = *(const s8v*)(hp + ks*32);
      #pragma unroll
      for (int g = 0; g < 4; ++g)
        #pragma unroll
        for (int ks = 0; ks < 8; ++ks) {
          s8v b = *(const s8v*)(wlds + ((size_t)((g*4 + u)*8 + ks))*1024 + l*16);
          acc[g] = __builtin_amdgcn_mfma_f32_16x16x32_bf16(a[ks], b, acc[g], 0, 0, 0);
        }
    }

    // epilogue: gates -> c,h ; h -> hexch (+fout at last step)
    const bool last = (t == T - 1);
    const int hd = q*64 + u*16 + c15;
    #pragma unroll
    for (int r = 0; r < 4; ++r) {
      const int row = ld4*4 + r;
      const char* gp = gbuf + s*8192 + row*128 + (u*16 + c15)*2;
      float pi = acc[0][r] + (float)*(const _Float16*)(gp);
      float pf = acc[1][r] + (float)*(const _Float16*)(gp + 2048);
      float pg = acc[2][r] + (float)*(const _Float16*)(gp + 4096);
      float po = acc[3][r] + (float)*(const _Float16*)(gp + 6144);
      float cn = sigm(pf) * cst[r] + sigm(pi) * tanh_f(pg);
      cst[r] = cn;
      float hv = sigm(po) * tanh_f(cn);
      const int grow = b0 + s*16 + row;
      hexch[((size_t)teff*256 + grow)*hstride + hcol + hd] = f2bf(hv);
      if (fout && last) fout[grow*512 + hd] = hv;
    }
    __syncthreads();   // stores drained (vmcnt0) + gbuf reads done
    if (tid == 0)
      __hip_atomic_fetch_add(cnt + t, 1, __ATOMIC_RELEASE, __HIP_MEMORY_SCOPE_AGENT);
  }
}

// ---------------- layer-1 backward: only its first step reaches the output --
__global__ __launch_bounds__(256) void bwd1_kernel(const _Float16* __restrict__ G,
                                                   float* __restrict__ out)
{
  int tid = blockIdx.x * 256 + threadIdx.x;   // 65536 = 256 b x 256 hd
  int b = tid >> 8, hd = tid & 255;
  const _Float16* g = G + ((size_t)(127*256 + b))*2048 + 1024;
  float pi = (float)g[hd];
  float pg = (float)g[512 + hd];
  float po = (float)g[768 + hd];
  float cn = sigm(pi) * tanh_f(pg);
  out[b*512 + 256 + hd] = sigm(po) * tanh_f(cn);
}

// ---------------- launch -----------------------------------------------------
extern "C" void kernel_launch(void* const* d_in, const int* in_sizes, int n_in,
                              void* d_out, int out_size, void* d_ws, size_t ws_size,
                              hipStream_t stream)
{
  (void)in_sizes; (void)n_in; (void)out_size; (void)ws_size;
  const int*   idc   = (const int*)d_in[0];
  const float* emb   = (const float*)d_in[1];
  const float* wih0f = (const float*)d_in[2];
  const float* whh0f = (const float*)d_in[3];
  const float* b0f   = (const float*)d_in[4];
  const float* wih0b = (const float*)d_in[5];
  const float* whh0b = (const float*)d_in[6];
  const float* b0b   = (const float*)d_in[7];
  const float* wih1f = (const float*)d_in[8];
  const float* whh1f = (const float*)d_in[9];
  const float* b1f   = (const float*)d_in[10];
  const float* wih1b = (const float*)d_in[11];
  const float* b1b   = (const float*)d_in[13];

  char* ws = (char*)d_ws;                                   // ~189.3 MB used
  unsigned short* X0   = (unsigned short*)(ws);             // 16,777,216 B (embeds; later scan1 hexch [128][256][256])
  unsigned short* Y0   = (unsigned short*)(ws + 16777216);  // 33,554,432 B (scan0 hexch == layer-1 input)
  _Float16*       Gb   = (_Float16*)(ws + 50331648);        // 134,217,728 B
  unsigned short* W0P  = (unsigned short*)(ws + 184549376); // 1,048,576 B
  unsigned short* W1P  = (unsigned short*)(ws + 185597952); // 2,097,152 B
  short*          WH0F = (short*)(ws + 187695104);          // 524,288 B
  short*          WH0B = (short*)(ws + 188219392);          // 524,288 B
  short*          WH1F = (short*)(ws + 188743680);          // 524,288 B
  float*          B0P  = (float*)(ws + 189267968);          // 8,192 B
  float*          B1P  = (float*)(ws + 189276160);          // 8,192 B
  int*            FLG0 = (int*)(ws + 189284352);            // [16][128] = 8,192 B
  int*            FLG1 = (int*)(ws + 189292544);            // [8][128]  = 4,096 B
  float* out = (float*)d_out;

  hipMemsetAsync(ws + 189284352, 0, 12288, stream);         // zero sync flags

  embed_kernel<<<dim3(4096), dim3(256), 0, stream>>>(idc, emb, X0);
  pack2_bf16<<<dim3(512),  dim3(256), 0, stream>>>(W0P, wih0f, wih0b, 262144);
  pack2_bf16<<<dim3(1024), dim3(256), 0, stream>>>(W1P, wih1f, wih1b, 524288);
  pack2_f32 <<<dim3(8),    dim3(256), 0, stream>>>(B0P, b0f, b0b, 1024);
  pack2_f32 <<<dim3(8),    dim3(256), 0, stream>>>(B1P, b1f, b1b, 1024);
  pack_whh  <<<dim3(128),  dim3(256), 0, stream>>>(WH0F, whh0f);
  pack_whh  <<<dim3(128),  dim3(256), 0, stream>>>(WH0B, whh0b);
  pack_whh  <<<dim3(128),  dim3(256), 0, stream>>>(WH1F, whh1f);

  // L0: full gate GEMM (both dirs) + split bi-directional scan (h via Y0)
  gemm_bt<<<dim3(256, 16), dim3(256), 0, stream>>>(X0, W0P, B0P, Gb, 256);
  scan_kernel<<<dim3(8, 2, 4), dim3(512), 0, stream>>>(
      Gb, WH0F, WH0B, Y0, 512, (float*)nullptr, FLG0, 128);

  // L1: fwd gates for all t (N=1024) + bwd gates only for t=127
  gemm_bt<<<dim3(256, 8), dim3(256), 0, stream>>>(Y0, W1P, B1P, Gb, 512);
  gemm_bt<<<dim3(2, 8), dim3(256), 0, stream>>>(
      Y0 + (size_t)127*256*512, W1P + (size_t)1024*512, B1P + 1024,
      Gb + (size_t)127*256*2048 + 1024, 512);

  // L1 fwd scan (h via dead X0 region, stride 256)
  scan_kernel<<<dim3(8, 1, 4), dim3(512), 0, stream>>>(
      Gb, WH1F, WH1F, X0, 256, out, FLG1, 128);
  bwd1_kernel<<<dim3(256), dim3(256), 0, stream>>>(Gb, out);
}